// Round 1
// baseline (425.690 us; speedup 1.0000x reference)
//
#include <hip/hip_runtime.h>

// Fused 7-layer 1x1-conv chain (128->64->32->16->8->4->2->1) with LeakyReLU(0.01)
// between layers. One thread per pixel; weights transposed to c-major in d_ws by a
// tiny pre-kernel so the main kernel's uniform weight reads are contiguous s_loads.

#define NEG_SLOPE 0.01f

__global__ void pack_w_kernel(const float* __restrict__ w1, const float* __restrict__ w2,
                              const float* __restrict__ w3, const float* __restrict__ w4,
                              const float* __restrict__ w5, const float* __restrict__ w6,
                              const float* __restrict__ w7, float* __restrict__ wt) {
    const float* ws[7] = {w1, w2, w3, w4, w5, w6, w7};
    const int O[7] = {64, 32, 16, 8, 4, 2, 1};
    const int C[7] = {128, 64, 32, 16, 8, 4, 2};
    int t  = blockIdx.x * blockDim.x + threadIdx.x;
    int nt = gridDim.x * blockDim.x;
    int off = 0;
    for (int l = 0; l < 7; ++l) {
        int n = O[l] * C[l];
        for (int i = t; i < n; i += nt) {
            int c = i / O[l];
            int o = i - c * O[l];
            // wt layout: [c][o] (c-major) so fixed-c weight vectors are contiguous
            wt[off + i] = ws[l][o * C[l] + c];
        }
        off += n;
    }
}

__device__ __forceinline__ float leaky(float v) { return v >= 0.f ? v : NEG_SLOPE * v; }

// Fully-unrolled dense layer: in[CIN] (registers) x wt[CIN][COUT] (c-major, uniform
// scalar loads) -> out[COUT]. All loops unrolled so register arrays never get a
// dynamic index (which would spill to scratch).
template <int CIN, int COUT>
__device__ __forceinline__ void dense(const float* __restrict__ wt,
                                      const float* __restrict__ in,
                                      float* __restrict__ out, bool act) {
#pragma unroll
    for (int o = 0; o < COUT; ++o) out[o] = 0.f;
#pragma unroll
    for (int c = 0; c < CIN; ++c) {
        float xv = in[c];
#pragma unroll
        for (int o = 0; o < COUT; ++o) out[o] = fmaf(wt[c * COUT + o], xv, out[o]);
    }
    if (act) {
#pragma unroll
        for (int o = 0; o < COUT; ++o) out[o] = leaky(out[o]);
    }
}

// wt offsets (floats): l1 @0 (128*64), l2 @8192 (64*32), l3 @10240 (32*16),
// l4 @10752 (16*8), l5 @10880 (8*4), l6 @10912 (4*2), l7 @10920 (2*1)
__global__ __launch_bounds__(256) void fused_chain_kernel(const float* __restrict__ x,
                                                          const float* __restrict__ wt,
                                                          float* __restrict__ out) {
    constexpr int HW = 65536;  // 256*256
    int g = blockIdx.x * 256 + threadIdx.x;  // global pixel id, exactly P threads
    int b = g >> 16;
    int p = g & (HW - 1);
    const float* xb = x + (size_t)b * 128 * HW + p;

    // Layer 1: 128 -> 64. c-loop rolled (indexes global memory only); inner 64 FMAs
    // unrolled; weight vector wt[c*64 .. c*64+63] is wave-uniform + contiguous.
    float h1[64];
#pragma unroll
    for (int o = 0; o < 64; ++o) h1[o] = 0.f;
    for (int c = 0; c < 128; ++c) {
        float xv = xb[(size_t)c * HW];  // coalesced: lane i -> consecutive addresses
        const float* wc = wt + c * 64;
#pragma unroll
        for (int o = 0; o < 64; ++o) h1[o] = fmaf(wc[o], xv, h1[o]);
    }
#pragma unroll
    for (int o = 0; o < 64; ++o) h1[o] = leaky(h1[o]);

    float h2[32];
    dense<64, 32>(wt + 8192, h1, h2, true);
    float h3[16];
    dense<32, 16>(wt + 10240, h2, h3, true);
    float h4[8];
    dense<16, 8>(wt + 10752, h3, h4, true);
    float h5[4];
    dense<8, 4>(wt + 10880, h4, h5, true);
    float h6[2];
    dense<4, 2>(wt + 10912, h5, h6, true);

    // Layer 7: 2 -> 1, no activation. out is (8,1,256,256) flat == g.
    out[g] = fmaf(wt[10920], h6[0], wt[10921] * h6[1]);
}

extern "C" void kernel_launch(void* const* d_in, const int* in_sizes, int n_in,
                              void* d_out, int out_size, void* d_ws, size_t ws_size,
                              hipStream_t stream) {
    const float* x  = (const float*)d_in[0];
    const float* w1 = (const float*)d_in[1];
    const float* w2 = (const float*)d_in[2];
    const float* w3 = (const float*)d_in[3];
    const float* w4 = (const float*)d_in[4];
    const float* w5 = (const float*)d_in[5];
    const float* w6 = (const float*)d_in[6];
    const float* w7 = (const float*)d_in[7];
    float* out = (float*)d_out;
    float* wt  = (float*)d_ws;  // 10922 floats = 43,688 bytes of scratch

    pack_w_kernel<<<32, 256, 0, stream>>>(w1, w2, w3, w4, w5, w6, w7, wt);

    const int P = 8 * 256 * 256;  // 524288 pixels
    fused_chain_kernel<<<P / 256, 256, 0, stream>>>(x, wt, out);
}